// Round 11
// baseline (312.999 us; speedup 1.0000x reference)
//
#include <hip/hip_runtime.h>
#include <math.h>

typedef unsigned short u16;
typedef short bf8 __attribute__((ext_vector_type(8)));      // 8 bf16 (raw bits)
typedef float f32x4 __attribute__((ext_vector_type(4)));

__device__ __forceinline__ u16 f2b(float f) {
    union { float f; unsigned u; } x; x.f = f;
    return (u16)((x.u + 0x7FFFu + ((x.u >> 16) & 1u)) >> 16);   // RTNE
}
__device__ __forceinline__ float b2f(u16 b) {
    union { unsigned u; float f; } x; x.u = ((unsigned)b) << 16;
    return x.f;
}

__device__ __forceinline__ void async16(const void* g, void* l) {
    __builtin_amdgcn_global_load_lds(
        (const __attribute__((address_space(1))) unsigned int*)g,
        (__attribute__((address_space(3))) unsigned int*)l, 16, 0, 0);
}

__device__ __forceinline__ void cstore(float* p, float v) { *p = v; }
__device__ __forceinline__ void cstore(u16* p, float v) { *p = f2b(v); }

// ---------------- bf16 MFMA GEMM (m97 structure): C[M,N] = A[M,K] @ Bt[N,K]^T ------
template<typename OutT>
__global__ __launch_bounds__(256) void gemm_mfma(const u16* __restrict__ A,
                                                 const u16* __restrict__ Bt,
                                                 OutT* __restrict__ C,
                                                 int M, int N, int K) {
    __shared__ __align__(16) u16 As[128 * 32];
    __shared__ __align__(16) u16 Bs[128 * 32];
    const int tid = threadIdx.x;
    const int w = tid >> 6, L = tid & 63;
    const int l15 = L & 15, quad = L >> 4;
    const int wm = (w >> 1) * 64, wn = (w & 1) * 64;
    const int row0 = blockIdx.y * 128, col0 = blockIdx.x * 128;
    const int laneRow = L >> 2, laneCol8 = (L & 3) * 8;

    f32x4 acc[4][4] = {};

    for (int k0 = 0; k0 < K; k0 += 32) {
        #pragma unroll
        for (int i = 0; i < 2; ++i) {
            const int seg = w * 2 + i;
            const int r = seg * 16 + laneRow;
            async16(&A[(size_t)(row0 + r) * K + k0 + laneCol8], &As[seg * 512 + L * 8]);
        }
        #pragma unroll
        for (int i = 0; i < 2; ++i) {
            const int seg = w * 2 + i;
            const int r = seg * 16 + laneRow;
            async16(&Bt[(size_t)(col0 + r) * K + k0 + laneCol8], &Bs[seg * 512 + L * 8]);
        }
        __syncthreads();
        bf8 a[4], b[4];
        #pragma unroll
        for (int mt = 0; mt < 4; ++mt)
            a[mt] = *(const bf8*)&As[(wm + mt * 16 + l15) * 32 + quad * 8];
        #pragma unroll
        for (int nt = 0; nt < 4; ++nt)
            b[nt] = *(const bf8*)&Bs[(wn + nt * 16 + l15) * 32 + quad * 8];
        #pragma unroll
        for (int mt = 0; mt < 4; ++mt)
            #pragma unroll
            for (int nt = 0; nt < 4; ++nt)
                acc[mt][nt] = __builtin_amdgcn_mfma_f32_16x16x32_bf16(
                    a[mt], b[nt], acc[mt][nt], 0, 0, 0);
        __syncthreads();
    }
    #pragma unroll
    for (int mt = 0; mt < 4; ++mt)
        #pragma unroll
        for (int nt = 0; nt < 4; ++nt) {
            const int col = col0 + wn + nt * 16 + l15;
            #pragma unroll
            for (int r = 0; r < 4; ++r) {
                const int row = row0 + wm + mt * 16 + quad * 4 + r;
                cstore(&C[(size_t)row * N + col], acc[mt][nt][r]);
            }
        }
}

// ---------------- merged prep: x->bf16, EKP/EVP fragment tables, weight transposes --
__global__ __launch_bounds__(256) void prep_all(const float* __restrict__ x,
                                                const float* __restrict__ embk,
                                                const float* __restrict__ embv,
                                                const float* __restrict__ w_attn,
                                                const float* __restrict__ w_proj,
                                                u16* __restrict__ xb,
                                                u16* __restrict__ EKP,
                                                u16* __restrict__ EVP,
                                                u16* __restrict__ waT,
                                                u16* __restrict__ wpT) {
    __shared__ u16 ts[64][65];
    const int bx = blockIdx.x;
    const int tid = threadIdx.x;
    if (bx < 4096) {
        int idx = bx * 256 + tid;
        const float4 v = ((const float4*)x)[idx];
        ((ushort4*)xb)[idx] = make_ushort4(f2b(v.x), f2b(v.y), f2b(v.z), f2b(v.w));
    } else if (bx < 4132) {
        int t = (bx - 4096) * 256 + tid;           // [0, 9216)
        int L = t & 63, kc = (t >> 6) & 1, k16 = t >> 7;
        int l15 = L & 15, quad = L >> 4;
        int row = 1 + k16 * 16 + l15;
        int d = row - 128;
        int cl = d < 0 ? 0 : (d > 1023 ? 1023 : d);
        const float* p = embk + cl * 64 + kc * 32 + quad * 8;
        #pragma unroll
        for (int i = 0; i < 8; ++i) EKP[t * 8 + i] = f2b(p[i]);
    } else if (bx < 4168) {
        int t = (bx - 4132) * 256 + tid;           // [0, 9216)
        int L = t & 63, rest = t >> 6;             // rest = tn*36 + c32
        int c32 = rest % 36, tn = rest / 36;
        int l15 = L & 15, quad = L >> 4;
        #pragma unroll
        for (int i = 0; i < 8; ++i) {
            int c = c32 * 32 + quad * 8 + i;
            int d = c - 127;
            int cl = d < 0 ? 0 : (d > 1023 ? 1023 : d);
            EVP[t * 8 + i] = f2b(embv[cl * 64 + tn * 16 + l15]);
        }
    } else {
        const float* W; u16* WT; int Cc, t;
        if (bx < 4168 + 768) { t = bx - 4168; W = w_attn; WT = waT; Cc = 3072; }
        else                 { t = bx - 4936; W = w_proj; WT = wpT; Cc = 1024; }
        const int nx = Cc >> 6;
        const int c0 = (t % nx) * 64, r0 = (t / nx) * 64;
        for (int i = tid; i < 4096; i += 256) {
            int r = i >> 6, c = i & 63;
            ts[r][c] = f2b(W[(size_t)(r0 + r) * Cc + c0 + c]);
        }
        __syncthreads();
        for (int i = tid; i < 4096; i += 256) {
            int c = i >> 6, r = i & 63;
            WT[(size_t)(c0 + c) * 1024 + r0 + r] = ts[r][c];
        }
    }
}

// ---------------- fused pack: qkvb -> Kp (scaled 1/8) + Vp fragment tables ----------
// grid (8 s-blocks of 128, 64 bh). V transposed through LDS (no Vt intermediate).
// Kp[bh][s16][kc][lane][8]; Vp[bh][tn][c32][lane][8] (frag elem k = c32*32+quad*8+i).
__global__ __launch_bounds__(256) void pack_kv(const u16* __restrict__ qkvb,
                                               u16* __restrict__ Kp,
                                               u16* __restrict__ Vp) {
    __shared__ __align__(16) u16 ts[128][72];     // stride 72: rows 16B-aligned, 2-way max
    const int tid = threadIdx.x;
    const int sb = blockIdx.x;
    const int bh = blockIdx.y, b = bh >> 4, h = bh & 15;
    const int s0 = sb * 128;
    const int L = tid & 63, fr0 = tid >> 6;
    const int l15 = L & 15, quad = L >> 4;

    // stage V rows [s0, s0+128) coalesced
    #pragma unroll
    for (int it = 0; it < 2; ++it) {
        const int row = it * 64 + (tid >> 2);
        const int c16 = (tid & 3) * 16;
        const u16* p = qkvb + (size_t)(b * 1024 + s0 + row) * 3072 + 2048 + h * 64 + c16;
        *(uint4*)&ts[row][c16]     = *(const uint4*)p;
        *(uint4*)&ts[row][c16 + 8] = *(const uint4*)(p + 8);
    }
    __syncthreads();

    // V fragments: wave fr0 emits frag-rows fr0*4..+4 (tn = fri>>2, c32loc = fri&3)
    #pragma unroll
    for (int k = 0; k < 4; ++k) {
        const int fri = fr0 * 4 + k;
        const int tn = fri >> 2, c32l = fri & 3;
        const int sl = c32l * 32 + quad * 8;
        __align__(16) u16 buf[8];
        #pragma unroll
        for (int i = 0; i < 8; ++i) buf[i] = ts[sl + i][tn * 16 + l15];
        const size_t fidx = (size_t)(bh * 4 + tn) * 32 + sb * 4 + c32l;
        *(uint4*)&Vp[fidx * 512 + L * 8] = *(uint4*)buf;
    }

    // K fragments (pre-scaled): fri = s16loc*2 + kc
    #pragma unroll
    for (int k = 0; k < 4; ++k) {
        const int fri = fr0 * 4 + k;
        const int s16 = sb * 8 + (fri >> 1), kc = fri & 1;
        const u16* src = qkvb + (size_t)(b * 1024 + s16 * 16 + l15) * 3072
                       + 1024 + h * 64 + kc * 32 + quad * 8;
        __align__(16) u16 buf[8];
        #pragma unroll
        for (int i = 0; i < 8; ++i) buf[i] = f2b(b2f(src[i]) * 0.125f);
        *(uint4*)&Kp[((size_t)(bh * 64 + s16) * 2 + kc) * 512 + L * 8] = *(uint4*)buf;
    }
}

// ---------------- MFMA fused attention with RPE: 128-col chunks, pair-balanced ------
// grid (8 pairs, 64 bh); block 256 = 4 waves, wave = 16 Q rows.
// S2 shear-gather done with ds_bpermute (src lane (row+15-l15)&15 same quad,
// register j = jA - tn, jA = 8 iff l15 < row) — no S2 LDS round-trip, S2 stays f32.
// P' pad band zeroed once per kernel (scatter addresses chunk-independent).
// Diagonal chunks (diff==0) trim S2/S1/PV/EV loops exactly (masked p=0 still
// scattered, so no stale LDS).
__global__ __launch_bounds__(256) void attn_mfma(const u16* __restrict__ qkvb,
                                                 const u16* __restrict__ Kp,
                                                 const u16* __restrict__ Vp,
                                                 const u16* __restrict__ EKP,
                                                 const u16* __restrict__ EVP,
                                                 u16* __restrict__ yb) {
    __shared__ __align__(16) u16 slab_[4][4608];   // per wave: Pl[0,2048) Ppl[2048,4608)
    __shared__ __align__(16) u16 KVs[16384];       // K frags [0..8192), V [8192..)

    const int tid = threadIdx.x;
    const int w = tid >> 6, L = tid & 63;
    const int l15 = L & 15, quad = L >> 4;
    const int pair = blockIdx.x;
    const int bh = blockIdx.y, b = bh >> 4, h = bh & 15;
    u16* Pl  = slab_[w];
    u16* Ppl = slab_[w] + 2048;

    const bf8* EKPF = (const bf8*)EKP;
    const bf8* EVPF = (const bf8*)EVP;

    // bpermute source-lane byte addresses (per r), same quad
    int gaddr[4];
    #pragma unroll
    for (int r = 0; r < 4; ++r) {
        const int row = quad * 4 + r;
        gaddr[r] = ((quad << 4) + ((row + 15 - l15) & 15)) << 2;
    }

    // one-time zero of the P' slab (pad band stays zero: scatter addrs chunk-indep)
    #pragma unroll
    for (int i = 0; i < 5; ++i)
        ((uint4*)Ppl)[i * 64 + L] = make_uint4(0, 0, 0, 0);

    #pragma unroll 1
    for (int half = 0; half < 2; ++half) {
        const int tile = half ? pair : (15 - pair);   // heavy tile first
        const int t0 = tile * 64;

        bf8 qn[2];
        {
            const int trow = t0 + w * 16 + l15;
            const u16* qp = qkvb + (size_t)(b * 1024 + trow) * 3072 + h * 64 + quad * 8;
            qn[0] = *(const bf8*)qp;
            qn[1] = *(const bf8*)(qp + 32);
        }

        f32x4 o[4] = {};
        float lsum[4] = {0.f, 0.f, 0.f, 0.f};

        const int nch = (t0 >> 7) + 1;
        #pragma unroll 1
        for (int c = 0; c < nch; ++c) {
            const int s0 = c << 7;
            const int diff = t0 - s0;                 // >= 0, multiple of 64
            const bool dg = (diff == 0);              // diagonal chunk

            __syncthreads();    // prior chunk's KVs reads retired

            // ---- issue K/V chunk DMA ----
            {
                const size_t kbase = ((size_t)(bh * 64 + (s0 >> 4)) << 1) * 512;
                #pragma unroll
                for (int i = 0; i < 4; ++i)
                    async16(Kp + kbase + (i * 256 + tid) * 8, &KVs[(i * 256 + tid) * 8]);
                const int vb = bh * 128 + (s0 >> 5);
                #pragma unroll
                for (int i = 0; i < 4; ++i)
                    async16(Vp + ((size_t)(vb + i * 32) * 512 + tid * 8),
                            &KVs[8192 + i * 2048 + tid * 8]);
            }

            // ---- S2 = Q @ EK^T (global EKP stream; overlaps the DMA) ----
            f32x4 s2[9] = {};
            {
                const int kb = (diff >> 4) + w;       // k16 base
                #pragma unroll
                for (int j = 0; j < 9; ++j) {
                    if (!(dg && j < 7 - w)) {
                        #pragma unroll
                        for (int kc = 0; kc < 2; ++kc)
                            s2[j] = __builtin_amdgcn_mfma_f32_16x16x32_bf16(
                                qn[kc], EKPF[(((kb + j) << 1) + kc) * 64 + L], s2[j], 0, 0, 0);
                    }
                }
            }

            __syncthreads();    // KVs DMA complete

            // ---- S1 = Q @ (K/8)^T from LDS ----
            f32x4 s1[8] = {};
            #pragma unroll
            for (int tn = 0; tn < 8; ++tn) {
                if (!(dg && tn > w)) {
                    #pragma unroll
                    for (int kc = 0; kc < 2; ++kc) {
                        const bf8 kf = *(const bf8*)&KVs[((tn << 1) + kc) * 512 + L * 8];
                        s1[tn] = __builtin_amdgcn_mfma_f32_16x16x32_bf16(
                            qn[kc], kf, s1[tn], 0, 0, 0);
                    }
                }
            }

            // ---- bpermute shear-gather + logits + exp + scatter, per r ----
            #pragma unroll
            for (int r = 0; r < 4; ++r) {
                const int row = quad * 4 + r;
                float g[9];
                #pragma unroll
                for (int j = 0; j < 9; ++j)
                    g[j] = __int_as_float(__builtin_amdgcn_ds_bpermute(
                        gaddr[r], __float_as_int(s2[j][r])));
                const bool hi = (l15 < row);          // jA == 8
                #pragma unroll
                for (int tn = 0; tn < 8; ++tn) {
                    const int cl = tn * 16 + l15;
                    float sv = hi ? g[8 - tn] : g[7 - tn];
                    float v = s1[tn][r] + sv;
                    if (cl > diff + w * 16 + row) v = -1e30f;
                    float p = __expf(v - 4.0f);       // masked -> 0
                    lsum[r] += p;
                    const u16 pb = f2b(p);
                    Pl[((cl >> 5) << 9) + (((cl >> 3) & 3) << 7) + (row << 3) + (cl & 7)] = pb;
                    const int dc = (w & 1) * 16 + row - cl + 127;   // [0,158]
                    Ppl[((dc >> 5) << 9) + (((dc >> 3) & 3) << 7) + (row << 3) + (dc & 7)] = pb;
                }
            }

            // ---- O += P @ V (V frags from LDS) ----
            {
                const int kcmax = dg ? (w >> 1) + 1 : 4;
                #pragma unroll
                for (int kc = 0; kc < 4; ++kc) {
                    if (kc < kcmax) {
                        const bf8 pa = ((const bf8*)Pl)[kc * 64 + L];
                        #pragma unroll
                        for (int tn = 0; tn < 4; ++tn) {
                            const bf8 vf = *(const bf8*)&KVs[8192 + (tn * 4 + kc) * 512 + L * 8];
                            o[tn] = __builtin_amdgcn_mfma_f32_16x16x32_bf16(
                                pa, vf, o[tn], 0, 0, 0);
                        }
                    }
                }
            }
            // ---- O += P' @ EV (global EVP stream) ----
            {
                const int e0 = dg ? ((w < 2) ? 3 : 2) : 0;
                const int eb = (diff >> 5) + (w >> 1);
                #pragma unroll
                for (int kc = 0; kc < 5; ++kc) {
                    if (kc >= e0) {
                        const bf8 pa = ((const bf8*)Ppl)[kc * 64 + L];
                        #pragma unroll
                        for (int tn = 0; tn < 4; ++tn)
                            o[tn] = __builtin_amdgcn_mfma_f32_16x16x32_bf16(
                                pa, EVPF[(tn * 36 + eb + kc) * 64 + L], o[tn], 0, 0, 0);
                    }
                }
            }
        }
        // ---- epilogue: one sum tree per row, then O / l ----
        #pragma unroll
        for (int r = 0; r < 4; ++r) {
            float ls = lsum[r];
            ls += __shfl_xor(ls, 1); ls += __shfl_xor(ls, 2);
            ls += __shfl_xor(ls, 4); ls += __shfl_xor(ls, 8);
            lsum[r] = ls;
        }
        #pragma unroll
        for (int tn = 0; tn < 4; ++tn) {
            const int col = h * 64 + tn * 16 + l15;
            #pragma unroll
            for (int r = 0; r < 4; ++r) {
                const int trow = t0 + w * 16 + quad * 4 + r;
                yb[(size_t)(b * 1024 + trow) * 1024 + col] = f2b(o[tn][r] / lsum[r]);
            }
        }
    }
}

extern "C" void kernel_launch(void* const* d_in, const int* in_sizes, int n_in,
                              void* d_out, int out_size, void* d_ws, size_t ws_size,
                              hipStream_t stream) {
    const float* x      = (const float*)d_in[0];
    const float* w_attn = (const float*)d_in[1];
    const float* w_proj = (const float*)d_in[2];
    const float* embk   = (const float*)d_in[3];
    const float* embv   = (const float*)d_in[4];
    float* out = (float*)d_out;

    u16* wsb   = (u16*)d_ws;
    u16* qkvb  = wsb;                  // 4096*3072            = 12582912
    u16* xb    = qkvb + 12582912;      // 4096*1024            = 4194304
    u16* ymidb = xb;                   // aliases xb (xb dead after gemm1)
    u16* waT   = xb + 4194304;         // 3072*1024            = 3145728
    u16* wpT   = waT + 3145728;        // 1024*1024            = 1048576
    u16* Kp    = wpT + 1048576;        // 64*64*2*512          = 4194304
    u16* Vp    = Kp + 4194304;         // 64*4*32*512          = 4194304
    u16* EKP   = Vp + 4194304;         // 72*2*512             = 73728
    u16* EVP   = EKP + 73728;          // 4*36*512             = 73728

    prep_all<<<dim3(5192), 256, 0, stream>>>(x, embk, embv, w_attn, w_proj,
                                             xb, EKP, EVP, waT, wpT);
    gemm_mfma<u16><<<dim3(24, 32), 256, 0, stream>>>(xb, waT, qkvb, 4096, 3072, 1024);
    pack_kv<<<dim3(8, 64), 256, 0, stream>>>(qkvb, Kp, Vp);
    attn_mfma<<<dim3(8, 64), 256, 0, stream>>>(qkvb, Kp, Vp, EKP, EVP, ymidb);
    gemm_mfma<float><<<dim3(8, 32), 256, 0, stream>>>(ymidb, wpT, out, 4096, 1024, 1024);
}